// Round 8
// baseline (175.157 us; speedup 1.0000x reference)
//
#include <hip/hip_runtime.h>
#include <stdint.h>

#define D_IN 2048
#define D_H  512
#define BM   32
#define NST  16   // stages of 128 k

typedef __attribute__((ext_vector_type(4)))  int i32x4;
typedef __attribute__((ext_vector_type(16))) int i32x16;

// Wt[n][k] = sign(W[k][n]) as +1/-1 int8 (1 MB). Reads coalesced across n.
__global__ __launch_bounds__(512) void pack_wt_kernel(
    const float* __restrict__ W, char* __restrict__ Wt) {
  const int n  = threadIdx.x;       // 0..511
  const int k0 = blockIdx.x * 32;   // 64 blocks
  uint words[8];
#pragma unroll
  for (int wq = 0; wq < 8; ++wq) {
    uint w = 0x01010101u;  // +1 bytes; negative -> XOR 0xFE -> 0xFF (-1)
#pragma unroll
    for (int j = 0; j < 4; ++j) {
      uint bits = __float_as_uint(W[(size_t)(k0 + wq * 4 + j) * D_H + n]);
      w ^= ((uint)((int)bits >> 31)) & (0xFEu << (8 * j));
    }
    words[wq] = w;
  }
  uint* dst = (uint*)(Wt + (size_t)n * D_IN + k0);
#pragma unroll
  for (int wq = 0; wq < 8; ++wq) dst[wq] = words[wq];
}

__device__ inline uint pack4(float4 v) {
  uint w = 0x01010101u;
  w ^= ((uint)((int)__float_as_uint(v.x) >> 31)) & 0x000000FEu;
  w ^= ((uint)((int)__float_as_uint(v.y) >> 31)) & 0x0000FE00u;
  w ^= ((uint)((int)__float_as_uint(v.z) >> 31)) & 0x00FE0000u;
  w ^= ((uint)((int)__float_as_uint(v.w) >> 31)) & 0xFE000000u;
  return w;
}

// Binary GEMM via v_mfma_i32_32x32x32_i8.
// Block: 512 thr / 8 waves, 32 rows x 512 cols (X read once). Wave wv owns
// cols [64wv, 64wv+64) = 2 MFMA tiles (acc = 32 VGPR).
// A (packed X signs) double-buffered in LDS per 128-k stage, XOR-swizzled
// (granule ^= row&7 on write AND read). Per stage: issue 8 B-loads (all 4
// steps, oldest in vmcnt) -> issue 2 X-loads for stage+1 (youngest) ->
// 4 steps of {1 ds_read_b128 A + 2 MFMA} -> pack+ds_write X -> barrier.
// B-waits never drain the X prefetch (in-order vmcnt retire).
__global__ __launch_bounds__(512, 1) void bgemm_kernel(
    const float* __restrict__ X, const char* __restrict__ Wt,
    const float* __restrict__ b, const float* __restrict__ beta,
    const float* __restrict__ mm, const float* __restrict__ mv,
    float* __restrict__ out) {
  __shared__ uint Xp[2][1024];  // 2 x 4KB packed A tiles
  char* lds0 = (char*)&Xp[0][0];

  const int tid = threadIdx.x;
  const int l   = tid & 63;
  const int wv  = tid >> 6;         // 0..7
  const int am  = l & 31;
  const int ah  = l >> 5;
  const size_t m0 = (size_t)blockIdx.x * BM;
  const int colbase = wv * 64;

  // stage-writer coords: row sr, 8-byte group shg (16 groups x 8B = 128B/row)
  const int sr  = tid >> 4;   // 0..31
  const int shg = tid & 15;   // 0..15
  const int swb = sr * 128 + (((shg >> 1) ^ (sr & 7)) << 4) + (shg & 1) * 8;
  const float4* Xrow = (const float4*)(X + (m0 + sr) * D_IN);

  // A-read swizzled byte offsets per step (granule 2s+ah, row am)
  const int arow = am * 128;
  const int akey = am & 7;

  // B pointers: tile t col = colbase + t*32 + am; 16B at k-offset 16*ah
  const char* Bp0 = Wt + (size_t)(colbase + am) * D_IN + 16 * ah;
  const char* Bp1 = Bp0 + (size_t)32 * D_IN;

  i32x16 acc0, acc1;
#pragma unroll
  for (int r = 0; r < 16; ++r) { acc0[r] = 0; acc1[r] = 0; }

  // ---- prologue: stage 0 staged directly ----
  float4 vq0 = Xrow[shg * 2];
  float4 vq1 = Xrow[shg * 2 + 1];
  {
    uint2 u; u.x = pack4(vq0); u.y = pack4(vq1);
    *(uint2*)(lds0 + swb) = u;
  }
  __syncthreads();

#pragma unroll 1
  for (int st = 0; st < NST; ++st) {
    char* buf = lds0 + (st & 1) * 4096;

    // 1) B loads for all 4 steps (oldest in vmcnt)
    const char* bp0 = Bp0 + st * 128;
    const char* bp1 = Bp1 + st * 128;
    i32x4 B0a = *(const i32x4*)(bp0 + 0 * 32);
    i32x4 B0b = *(const i32x4*)(bp1 + 0 * 32);
    i32x4 B1a = *(const i32x4*)(bp0 + 1 * 32);
    i32x4 B1b = *(const i32x4*)(bp1 + 1 * 32);
    i32x4 B2a = *(const i32x4*)(bp0 + 2 * 32);
    i32x4 B2b = *(const i32x4*)(bp1 + 2 * 32);
    i32x4 B3a = *(const i32x4*)(bp0 + 3 * 32);
    i32x4 B3b = *(const i32x4*)(bp1 + 3 * 32);

    // 2) X loads for stage st+1 (youngest; consumed after the 4 steps)
    if (st + 1 < NST) {
      vq0 = Xrow[(st + 1) * 32 + shg * 2];
      vq1 = Xrow[(st + 1) * 32 + shg * 2 + 1];
    }

    // 3) 4 k-steps: A from LDS (swizzled), 2 MFMA each
    {
      i32x4 a = *(const i32x4*)(buf + arow + (((0 + ah) ^ akey) << 4));
      acc0 = __builtin_amdgcn_mfma_i32_32x32x32_i8(a, B0a, acc0, 0, 0, 0);
      acc1 = __builtin_amdgcn_mfma_i32_32x32x32_i8(a, B0b, acc1, 0, 0, 0);
    }
    {
      i32x4 a = *(const i32x4*)(buf + arow + (((2 + ah) ^ akey) << 4));
      acc0 = __builtin_amdgcn_mfma_i32_32x32x32_i8(a, B1a, acc0, 0, 0, 0);
      acc1 = __builtin_amdgcn_mfma_i32_32x32x32_i8(a, B1b, acc1, 0, 0, 0);
    }
    {
      i32x4 a = *(const i32x4*)(buf + arow + (((4 + ah) ^ akey) << 4));
      acc0 = __builtin_amdgcn_mfma_i32_32x32x32_i8(a, B2a, acc0, 0, 0, 0);
      acc1 = __builtin_amdgcn_mfma_i32_32x32x32_i8(a, B2b, acc1, 0, 0, 0);
    }
    {
      i32x4 a = *(const i32x4*)(buf + arow + (((6 + ah) ^ akey) << 4));
      acc0 = __builtin_amdgcn_mfma_i32_32x32x32_i8(a, B3a, acc0, 0, 0, 0);
      acc1 = __builtin_amdgcn_mfma_i32_32x32x32_i8(a, B3b, acc1, 0, 0, 0);
    }

    // 4) pack + write next stage's A tile
    if (st + 1 < NST) {
      uint2 u; u.x = pack4(vq0); u.y = pack4(vq1);
      *(uint2*)(lds0 + ((st + 1) & 1) * 4096 + swb) = u;
    }
    __syncthreads();
  }

  // ---- epilogue: out = (dot + b - mean) * rsqrt(var+eps) + beta ----
  // D layout (verified R7): col = am (+tile base), row = (r&3) + 8*(r>>2) + 4*ah
  const int rb = 4 * ah;
#pragma unroll
  for (int nt = 0; nt < 2; ++nt) {
    const i32x16 A = (nt == 0) ? acc0 : acc1;
    const int c = colbase + nt * 32 + am;
    const float bb  = b[c];
    const float mmc = mm[c];
    const float bec = beta[c];
    const float inv = rsqrtf(mv[c] + 1e-3f);
#pragma unroll
    for (int r = 0; r < 16; ++r) {
      const int row = (r & 3) + 8 * (r >> 2) + rb;
      out[(m0 + row) * D_H + c] = ((float)A[r] + bb - mmc) * inv + bec;
    }
  }
}

extern "C" void kernel_launch(void* const* d_in, const int* in_sizes, int n_in,
                              void* d_out, int out_size, void* d_ws, size_t ws_size,
                              hipStream_t stream) {
  const float* X    = (const float*)d_in[0];  // [32768, 2048]
  const float* W    = (const float*)d_in[1];  // [2048, 512]
  const float* b    = (const float*)d_in[2];  // [512]
  const float* beta = (const float*)d_in[3];  // [512]
  const float* mm   = (const float*)d_in[4];  // [512]
  const float* mv   = (const float*)d_in[5];  // [512]
  float* out = (float*)d_out;                 // [32768, 512]

  char* Wt = (char*)d_ws;  // [512][2048] i8 = 1 MB

  pack_wt_kernel<<<dim3(D_IN / 32), dim3(D_H), 0, stream>>>(W, Wt);

  const int M = in_sizes[0] / D_IN;  // 32768
  bgemm_kernel<<<dim3(M / BM), dim3(512), 0, stream>>>(X, Wt, b, beta, mm, mv, out);
}

// Round 9
// 120.657 us; speedup vs baseline: 1.4517x; 1.4517x over previous
//
#include <hip/hip_runtime.h>
#include <stdint.h>

#define D_IN 2048
#define D_H  512
#define BM   32
#define NST  16   // stages of 128 k

typedef __attribute__((ext_vector_type(4)))  int i32x4;
typedef __attribute__((ext_vector_type(16))) int i32x16;

// Wfrag[sg][t][l][16] : byte j = sign(W[sg*32 + 16*(l>>5) + j][t*32 + (l&31)])
// -> every GEMM B-load is 64 lanes x 16B = 1KB contiguous.
__global__ __launch_bounds__(1024) void pack_wt_kernel(
    const float* __restrict__ W, char* __restrict__ Wf) {
  const int s = blockIdx.x;          // 0..63  (k-step)
  const int t = threadIdx.x >> 6;    // 0..15  (col tile)
  const int l = threadIdx.x & 63;    // lane
  const int n = t * 32 + (l & 31);
  const int kbase = s * 32 + 16 * (l >> 5);
  uint wq[4];
#pragma unroll
  for (int q = 0; q < 4; ++q) {
    uint w = 0x01010101u;  // +1 bytes; negative -> XOR 0xFE -> 0xFF (-1)
#pragma unroll
    for (int j = 0; j < 4; ++j) {
      uint bits = __float_as_uint(W[(size_t)(kbase + 4 * q + j) * D_H + n]);
      w ^= ((uint)((int)bits >> 31)) & (0xFEu << (8 * j));
    }
    wq[q] = w;
  }
  *(uint4*)(Wf + ((size_t)(s * 16 + t) * 64 + l) * 16) =
      make_uint4(wq[0], wq[1], wq[2], wq[3]);
}

__device__ __forceinline__ uint pack4(float4 v) {
  uint w = 0x01010101u;
  w ^= ((uint)((int)__float_as_uint(v.x) >> 31)) & 0x000000FEu;
  w ^= ((uint)((int)__float_as_uint(v.y) >> 31)) & 0x0000FE00u;
  w ^= ((uint)((int)__float_as_uint(v.z) >> 31)) & 0x00FE0000u;
  w ^= ((uint)((int)__float_as_uint(v.w) >> 31)) & 0xFE000000u;
  return w;
}

// Binary GEMM via v_mfma_i32_32x32x32_i8.
// Block: 512 thr / 8 waves, 32 rows x 512 cols (X read once, pack shared via
// LDS). Wave wv owns cols [64wv,64wv+64) = 2 tiles. All global loads are
// contiguous per wave-instruction (B: 1KB frag-ordered; X: 2x512B row runs).
// A-tile XOR-swizzled in LDS (same involution write & read). X prefetch
// depth 2 via named pairs P0/P1 (even/odd bodies, no runtime reg indexing).
// Per stage: issue B(st) (oldest) -> issue X(st+2) (youngest) -> 4 k-steps of
// {ds_read_b128 A, 2 MFMA} -> pack X(st+1) -> ds_write -> barrier.
__global__ __launch_bounds__(512, 1) void bgemm_kernel(
    const float* __restrict__ X, const char* __restrict__ Wf,
    const float* __restrict__ b, const float* __restrict__ beta,
    const float* __restrict__ mm, const float* __restrict__ mv,
    float* __restrict__ out) {
  __shared__ __align__(16) char XpL[2][4096];  // 2 x (32 rows x 128 k-bytes)

  const int tid = threadIdx.x;
  const int l   = tid & 63;
  const int wv  = tid >> 6;        // 0..7
  const int am  = l & 31;
  const int ah  = l >> 5;
  const size_t m0 = (size_t)blockIdx.x * BM;
  const int colbase = wv * 64;

  // X loader: thread -> row r0 = tid>>5 (and r0+16), k-float (tid&31)*4
  const float* Xt = X + (m0 + (tid >> 5)) * D_IN + (tid & 31) * 4;
  // LDS write addr (swizzled): granule gw = (tid&31)>>2, key = row&7
  const int r0  = tid >> 5;
  const int ws0 = r0 * 128 + (((((tid & 31) >> 2)) ^ (r0 & 7)) << 4) + (tid & 3) * 4;
  const int ws1 = ws0 + 16 * 128;  // row r0+16 (same key: (r0+16)&7 == r0&7)

  // LDS read: row am, granule (2s'+ah)^(am&7)
  const int arow = am * 128;
  const int akey = am & 7;

  // B base: Wfrag + sg*16384 + t*1024 + l*16 ; sg = st*4 + s'
  const char* Bbase0 = Wf + (size_t)(2 * wv) * 1024 + l * 16;      // tile t0
  const char* Bbase1 = Wf + (size_t)(2 * wv + 1) * 1024 + l * 16;  // tile t1

  i32x16 acc0, acc1;
#pragma unroll
  for (int r = 0; r < 16; ++r) { acc0[r] = 0; acc1[r] = 0; }

  float4 P0a, P0b, P1a, P1b;  // prefetch pairs (stage parity = name parity)

  // ---- prologue: stage 0 direct; issue X(1) -> P1 ----
  {
    float4 q0 = *(const float4*)(Xt);
    float4 q1 = *(const float4*)(Xt + 16 * D_IN);
    *(uint*)(XpL[0] + ws0) = pack4(q0);
    *(uint*)(XpL[0] + ws1) = pack4(q1);
    P1a = *(const float4*)(Xt + 1 * 128);
    P1b = *(const float4*)(Xt + 1 * 128 + 16 * D_IN);
  }
  __syncthreads();

#define STAGE_BODY(ST, BUF, PIa, PIb, PCa, PCb, PREF, PACK)                   \
  do {                                                                        \
    const char* bs = Wf + (size_t)(ST) * 65536;                               \
    const char* b0 = Bbase0 + (size_t)(ST) * 65536;                           \
    const char* b1 = Bbase1 + (size_t)(ST) * 65536;                           \
    (void)bs;                                                                 \
    i32x4 B0a = *(const i32x4*)(b0 + 0 * 16384);                              \
    i32x4 B0b = *(const i32x4*)(b1 + 0 * 16384);                              \
    i32x4 B1a = *(const i32x4*)(b0 + 1 * 16384);                              \
    i32x4 B1b = *(const i32x4*)(b1 + 1 * 16384);                              \
    i32x4 B2a = *(const i32x4*)(b0 + 2 * 16384);                              \
    i32x4 B2b = *(const i32x4*)(b1 + 2 * 16384);                              \
    i32x4 B3a = *(const i32x4*)(b0 + 3 * 16384);                              \
    i32x4 B3b = *(const i32x4*)(b1 + 3 * 16384);                              \
    if (PREF) {                                                               \
      PIa = *(const float4*)(Xt + ((ST) + 2) * 128);                          \
      PIb = *(const float4*)(Xt + ((ST) + 2) * 128 + 16 * D_IN);              \
    }                                                                         \
    {                                                                         \
      i32x4 a = *(const i32x4*)(XpL[BUF] + arow + (((0 + ah) ^ akey) << 4));  \
      acc0 = __builtin_amdgcn_mfma_i32_32x32x32_i8(a, B0a, acc0, 0, 0, 0);    \
      acc1 = __builtin_amdgcn_mfma_i32_32x32x32_i8(a, B0b, acc1, 0, 0, 0);    \
    }                                                                         \
    {                                                                         \
      i32x4 a = *(const i32x4*)(XpL[BUF] + arow + (((2 + ah) ^ akey) << 4));  \
      acc0 = __builtin_amdgcn_mfma_i32_32x32x32_i8(a, B1a, acc0, 0, 0, 0);    \
      acc1 = __builtin_amdgcn_mfma_i32_32x32x32_i8(a, B1b, acc1, 0, 0, 0);    \
    }                                                                         \
    {                                                                         \
      i32x4 a = *(const i32x4*)(XpL[BUF] + arow + (((4 + ah) ^ akey) << 4));  \
      acc0 = __builtin_amdgcn_mfma_i32_32x32x32_i8(a, B2a, acc0, 0, 0, 0);    \
      acc1 = __builtin_amdgcn_mfma_i32_32x32x32_i8(a, B2b, acc1, 0, 0, 0);    \
    }                                                                         \
    {                                                                         \
      i32x4 a = *(const i32x4*)(XpL[BUF] + arow + (((6 + ah) ^ akey) << 4));  \
      acc0 = __builtin_amdgcn_mfma_i32_32x32x32_i8(a, B3a, acc0, 0, 0, 0);    \
      acc1 = __builtin_amdgcn_mfma_i32_32x32x32_i8(a, B3b, acc1, 0, 0, 0);    \
    }                                                                         \
    if (PACK) {                                                               \
      *(uint*)(XpL[(BUF) ^ 1] + ws0) = pack4(PCa);                            \
      *(uint*)(XpL[(BUF) ^ 1] + ws1) = pack4(PCb);                            \
      __syncthreads();                                                        \
    }                                                                         \
  } while (0)

#pragma unroll 1
  for (int st = 0; st < NST - 2; st += 2) {
    STAGE_BODY(st,     0, P0a, P0b, P1a, P1b, true, true);  // even: issue->P0
    STAGE_BODY(st + 1, 1, P1a, P1b, P0a, P0b, true, true);  // odd:  issue->P1
  }
  STAGE_BODY(NST - 2, 0, P0a, P0b, P1a, P1b, false, true);  // stage 14
  STAGE_BODY(NST - 1, 1, P1a, P1b, P0a, P0b, false, false); // stage 15
#undef STAGE_BODY

  // ---- epilogue: out = (dot + b - mean) * rsqrt(var+eps) + beta ----
  // D layout (verified R7/R8): col = am, row = (r&3) + 8*(r>>2) + 4*ah
  const int rb = 4 * ah;
#pragma unroll
  for (int nt = 0; nt < 2; ++nt) {
    const i32x16 A = (nt == 0) ? acc0 : acc1;
    const int c = colbase + nt * 32 + am;
    const float bb  = b[c];
    const float mmc = mm[c];
    const float bec = beta[c];
    const float inv = rsqrtf(mv[c] + 1e-3f);
#pragma unroll
    for (int r = 0; r < 16; ++r) {
      const int row = (r & 3) + 8 * (r >> 2) + rb;
      out[(m0 + row) * D_H + c] = ((float)A[r] + bb - mmc) * inv + bec;
    }
  }
}

extern "C" void kernel_launch(void* const* d_in, const int* in_sizes, int n_in,
                              void* d_out, int out_size, void* d_ws, size_t ws_size,
                              hipStream_t stream) {
  const float* X    = (const float*)d_in[0];  // [32768, 2048]
  const float* W    = (const float*)d_in[1];  // [2048, 512]
  const float* b    = (const float*)d_in[2];  // [512]
  const float* beta = (const float*)d_in[3];  // [512]
  const float* mm   = (const float*)d_in[4];  // [512]
  const float* mv   = (const float*)d_in[5];  // [512]
  float* out = (float*)d_out;                 // [32768, 512]

  char* Wf = (char*)d_ws;  // frag-ordered W signs, 1 MB

  pack_wt_kernel<<<dim3(D_IN / 32), dim3(1024), 0, stream>>>(W, Wf);

  const int M = in_sizes[0] / D_IN;  // 32768
  bgemm_kernel<<<dim3(M / BM), dim3(512), 0, stream>>>(X, Wf, b, beta, mm, mv, out);
}

// Round 10
// 88.685 us; speedup vs baseline: 1.9750x; 1.3605x over previous
//
#include <hip/hip_runtime.h>
#include <stdint.h>

#define D_IN 2048
#define D_H  512
#define BM   64
#define NST  16   // stages of 128 k

typedef __attribute__((ext_vector_type(4)))  int i32x4;
typedef __attribute__((ext_vector_type(16))) int i32x16;

// Wfrag[sg][t][l][16] : byte j = sign(W[sg*32 + 16*(l>>5) + j][t*32 + (l&31)])
// -> every GEMM B-load is 64 lanes x 16B = 1KB contiguous.
__global__ __launch_bounds__(1024) void pack_wt_kernel(
    const float* __restrict__ W, char* __restrict__ Wf) {
  const int s = blockIdx.x;          // 0..63  (k-step)
  const int t = threadIdx.x >> 6;    // 0..15  (col tile)
  const int l = threadIdx.x & 63;    // lane
  const int n = t * 32 + (l & 31);
  const int kbase = s * 32 + 16 * (l >> 5);
  uint wq[4];
#pragma unroll
  for (int q = 0; q < 4; ++q) {
    uint w = 0x01010101u;  // +1 bytes; negative -> XOR 0xFE -> 0xFF (-1)
#pragma unroll
    for (int j = 0; j < 4; ++j) {
      uint bits = __float_as_uint(W[(size_t)(kbase + 4 * q + j) * D_H + n]);
      w ^= ((uint)((int)bits >> 31)) & (0xFEu << (8 * j));
    }
    wq[q] = w;
  }
  *(uint4*)(Wf + ((size_t)(s * 16 + t) * 64 + l) * 16) =
      make_uint4(wq[0], wq[1], wq[2], wq[3]);
}

__device__ __forceinline__ uint pack4(float4 v) {
  uint w = 0x01010101u;
  w ^= ((uint)((int)__float_as_uint(v.x) >> 31)) & 0x000000FEu;
  w ^= ((uint)((int)__float_as_uint(v.y) >> 31)) & 0x0000FE00u;
  w ^= ((uint)((int)__float_as_uint(v.z) >> 31)) & 0x00FE0000u;
  w ^= ((uint)((int)__float_as_uint(v.w) >> 31)) & 0xFE000000u;
  return w;
}

// Binary GEMM via v_mfma_i32_32x32x32_i8.
// Block: 512 thr / 8 waves, 64 rows x 512 cols. Wave wv owns ALL 64 rows x
// cols [64wv,64wv+64): per k-step 2 A-frags (row halves) x 2 B-frags -> 4
// MFMA; acc = 4 x i32x16. Per stage (128 k): 8 B-loads (1KB contig, oldest
// in vmcnt) -> 4 X-loads (512B runs, youngest; depth-1 prefetch) -> 4 k-steps
// {2 ds_read_b128 A, 4 MFMA} -> pack X -> 4 ds_write -> barrier.
__global__ __launch_bounds__(512) void bgemm_kernel(
    const float* __restrict__ X, const char* __restrict__ Wf,
    const float* __restrict__ b, const float* __restrict__ beta,
    const float* __restrict__ mm, const float* __restrict__ mv,
    float* __restrict__ out) {
  __shared__ __align__(16) char XpL[2][8192];  // 2 x (64 rows x 128 k-bytes)

  const int tid = threadIdx.x;
  const int l   = tid & 63;
  const int wv  = tid >> 6;        // 0..7
  const int am  = l & 31;
  const int ah  = l >> 5;
  const size_t m0 = (size_t)blockIdx.x * BM;
  const int colbase = wv * 64;

  // X loader: thread -> rows r0+{0,16,32,48}, float4 index kw within slice
  const int r0 = tid >> 5;   // 0..15
  const int kw = tid & 31;   // 0..31
  const float* Xt = X + (m0 + r0) * D_IN + kw * 4;

  // LDS write byte offset for row r0 (rows +16i share the key: 16 = 0 mod 8)
  const int ws0 = r0 * 128 + (((kw >> 2) ^ (r0 & 7)) << 4) + (kw & 3) * 4;

  // LDS read: row halves at am and am+32 (same key am&7)
  const int arow0 = am * 128;
  const int arow1 = arow0 + 32 * 128;
  const int akey  = am & 7;

  // B pointers: tiles 2wv, 2wv+1; load for (st,s') at + st*65536 + s'*16384
  const char* Bb0 = Wf + (size_t)(2 * wv) * 1024 + (size_t)l * 16;
  const char* Bb1 = Bb0 + 1024;

  i32x16 acc00, acc01, acc10, acc11;  // [rowhalf][tile]
#pragma unroll
  for (int r = 0; r < 16; ++r) { acc00[r] = 0; acc01[r] = 0; acc10[r] = 0; acc11[r] = 0; }

  float4 vxa, vxb, vxc, vxd;

  // ---- prologue: stage 0 loaded + packed directly ----
  vxa = *(const float4*)(Xt);
  vxb = *(const float4*)(Xt + 16 * D_IN);
  vxc = *(const float4*)(Xt + 32 * D_IN);
  vxd = *(const float4*)(Xt + 48 * D_IN);
  *(uint*)(XpL[0] + ws0)        = pack4(vxa);
  *(uint*)(XpL[0] + ws0 + 2048) = pack4(vxb);
  *(uint*)(XpL[0] + ws0 + 4096) = pack4(vxc);
  *(uint*)(XpL[0] + ws0 + 6144) = pack4(vxd);
  __syncthreads();

#pragma unroll 1
  for (int st = 0; st < NST; ++st) {
    const char* buf = &XpL[st & 1][0];
    const size_t so = (size_t)st * 65536;

    // 1) all 8 B-loads (oldest in vmcnt; waits on them never touch X)
    i32x4 B0a = *(const i32x4*)(Bb0 + so + 0 * 16384);
    i32x4 B0b = *(const i32x4*)(Bb1 + so + 0 * 16384);
    i32x4 B1a = *(const i32x4*)(Bb0 + so + 1 * 16384);
    i32x4 B1b = *(const i32x4*)(Bb1 + so + 1 * 16384);
    i32x4 B2a = *(const i32x4*)(Bb0 + so + 2 * 16384);
    i32x4 B2b = *(const i32x4*)(Bb1 + so + 2 * 16384);
    i32x4 B3a = *(const i32x4*)(Bb0 + so + 3 * 16384);
    i32x4 B3b = *(const i32x4*)(Bb1 + so + 3 * 16384);

    // 2) X for stage st+1 (youngest; consumed at stage end)
    if (st + 1 < NST) {
      const float* xp = Xt + (st + 1) * 128;
      vxa = *(const float4*)(xp);
      vxb = *(const float4*)(xp + 16 * D_IN);
      vxc = *(const float4*)(xp + 32 * D_IN);
      vxd = *(const float4*)(xp + 48 * D_IN);
    }

    // 3) 4 k-steps
    {
      i32x4 a0 = *(const i32x4*)(buf + arow0 + (((0 + ah) ^ akey) << 4));
      i32x4 a1 = *(const i32x4*)(buf + arow1 + (((0 + ah) ^ akey) << 4));
      acc00 = __builtin_amdgcn_mfma_i32_32x32x32_i8(a0, B0a, acc00, 0, 0, 0);
      acc10 = __builtin_amdgcn_mfma_i32_32x32x32_i8(a1, B0a, acc10, 0, 0, 0);
      acc01 = __builtin_amdgcn_mfma_i32_32x32x32_i8(a0, B0b, acc01, 0, 0, 0);
      acc11 = __builtin_amdgcn_mfma_i32_32x32x32_i8(a1, B0b, acc11, 0, 0, 0);
    }
    {
      i32x4 a0 = *(const i32x4*)(buf + arow0 + (((2 + ah) ^ akey) << 4));
      i32x4 a1 = *(const i32x4*)(buf + arow1 + (((2 + ah) ^ akey) << 4));
      acc00 = __builtin_amdgcn_mfma_i32_32x32x32_i8(a0, B1a, acc00, 0, 0, 0);
      acc10 = __builtin_amdgcn_mfma_i32_32x32x32_i8(a1, B1a, acc10, 0, 0, 0);
      acc01 = __builtin_amdgcn_mfma_i32_32x32x32_i8(a0, B1b, acc01, 0, 0, 0);
      acc11 = __builtin_amdgcn_mfma_i32_32x32x32_i8(a1, B1b, acc11, 0, 0, 0);
    }
    {
      i32x4 a0 = *(const i32x4*)(buf + arow0 + (((4 + ah) ^ akey) << 4));
      i32x4 a1 = *(const i32x4*)(buf + arow1 + (((4 + ah) ^ akey) << 4));
      acc00 = __builtin_amdgcn_mfma_i32_32x32x32_i8(a0, B2a, acc00, 0, 0, 0);
      acc10 = __builtin_amdgcn_mfma_i32_32x32x32_i8(a1, B2a, acc10, 0, 0, 0);
      acc01 = __builtin_amdgcn_mfma_i32_32x32x32_i8(a0, B2b, acc01, 0, 0, 0);
      acc11 = __builtin_amdgcn_mfma_i32_32x32x32_i8(a1, B2b, acc11, 0, 0, 0);
    }
    {
      i32x4 a0 = *(const i32x4*)(buf + arow0 + (((6 + ah) ^ akey) << 4));
      i32x4 a1 = *(const i32x4*)(buf + arow1 + (((6 + ah) ^ akey) << 4));
      acc00 = __builtin_amdgcn_mfma_i32_32x32x32_i8(a0, B3a, acc00, 0, 0, 0);
      acc10 = __builtin_amdgcn_mfma_i32_32x32x32_i8(a1, B3a, acc10, 0, 0, 0);
      acc01 = __builtin_amdgcn_mfma_i32_32x32x32_i8(a0, B3b, acc01, 0, 0, 0);
      acc11 = __builtin_amdgcn_mfma_i32_32x32x32_i8(a1, B3b, acc11, 0, 0, 0);
    }

    // 4) pack + write next stage's A tile
    if (st + 1 < NST) {
      char* nbuf = &XpL[(st + 1) & 1][0];
      *(uint*)(nbuf + ws0)        = pack4(vxa);
      *(uint*)(nbuf + ws0 + 2048) = pack4(vxb);
      *(uint*)(nbuf + ws0 + 4096) = pack4(vxc);
      *(uint*)(nbuf + ws0 + 6144) = pack4(vxd);
    }
    __syncthreads();
  }

  // ---- epilogue: out = (dot + b - mean) * rsqrt(var+eps) + beta ----
  // D layout (verified): col = tile base + am, row = (r&3)+8*(r>>2)+4*ah (+32h)
  const int rb = 4 * ah;
#pragma unroll
  for (int h = 0; h < 2; ++h) {
#pragma unroll
    for (int nt = 0; nt < 2; ++nt) {
      const i32x16 A = (h == 0) ? ((nt == 0) ? acc00 : acc01)
                                : ((nt == 0) ? acc10 : acc11);
      const int c = colbase + nt * 32 + am;
      const float bb  = b[c];
      const float mmc = mm[c];
      const float bec = beta[c];
      const float inv = rsqrtf(mv[c] + 1e-3f);
#pragma unroll
      for (int r = 0; r < 16; ++r) {
        const int row = (r & 3) + 8 * (r >> 2) + rb + 32 * h;
        out[(m0 + row) * D_H + c] = ((float)A[r] + bb - mmc) * inv + bec;
      }
    }
  }
}

extern "C" void kernel_launch(void* const* d_in, const int* in_sizes, int n_in,
                              void* d_out, int out_size, void* d_ws, size_t ws_size,
                              hipStream_t stream) {
  const float* X    = (const float*)d_in[0];  // [32768, 2048]
  const float* W    = (const float*)d_in[1];  // [2048, 512]
  const float* b    = (const float*)d_in[2];  // [512]
  const float* beta = (const float*)d_in[3];  // [512]
  const float* mm   = (const float*)d_in[4];  // [512]
  const float* mv   = (const float*)d_in[5];  // [512]
  float* out = (float*)d_out;                 // [32768, 512]

  char* Wf = (char*)d_ws;  // frag-ordered W signs, 1 MB

  pack_wt_kernel<<<dim3(D_IN / 32), dim3(1024), 0, stream>>>(W, Wf);

  const int M = in_sizes[0] / D_IN;  // 32768
  bgemm_kernel<<<dim3(M / BM), dim3(512), 0, stream>>>(X, Wf, b, beta, mm, mv, out);
}